// Round 3
// baseline (540.793 us; speedup 1.0000x reference)
//
#include <hip/hip_runtime.h>
#include <hip/hip_bf16.h>
#include <math.h>

#define NUM_USERS 60000
#define NUM_ITEMS 40000
#define NUM_NODES (NUM_USERS + NUM_ITEMS)
#define NNZ 2000000
#define DIM 64
#define BATCH 4096
#define TEMP_INV 5.0f   // 1/0.2
#define SCAN_BLOCKS ((NUM_NODES + 1023) / 1024)   // 98

typedef __attribute__((ext_vector_type(8))) __bf16 bf16x8;
typedef __attribute__((ext_vector_type(4))) float f32x4;

// ---------------- CSR build ----------------

__global__ void hist_kernel(const int* __restrict__ row, int* __restrict__ cnt,
                            int* __restrict__ rank, int nnz) {
    int stride = gridDim.x * blockDim.x;
    for (int e = blockIdx.x * blockDim.x + threadIdx.x; e < nnz; e += stride)
        rank[e] = atomicAdd(&cnt[row[e]], 1);
}

__global__ __launch_bounds__(1024) void scan1_kernel(const int* __restrict__ cnt,
        int* __restrict__ ptr, int* __restrict__ bsum, int n) {
    __shared__ int sh[1024];
    int t = threadIdx.x;
    int i = blockIdx.x * 1024 + t;
    int v = (i < n) ? cnt[i] : 0;
    sh[t] = v;
    __syncthreads();
    for (int d = 1; d < 1024; d <<= 1) {
        int w = (t >= d) ? sh[t - d] : 0;
        __syncthreads();
        sh[t] += w;
        __syncthreads();
    }
    int incl = sh[t];
    if (i < n) ptr[i] = incl - v;
    if (t == 1023) bsum[blockIdx.x] = incl;
}

__global__ __launch_bounds__(128) void scan2_kernel(const int* __restrict__ bsum,
        int* __restrict__ boffs, int* __restrict__ ptr, int nb, int n) {
    __shared__ int sh[128];
    int t = threadIdx.x;
    int v = (t < nb) ? bsum[t] : 0;
    sh[t] = v;
    __syncthreads();
    for (int d = 1; d < 128; d <<= 1) {
        int w = (t >= d) ? sh[t - d] : 0;
        __syncthreads();
        sh[t] += w;
        __syncthreads();
    }
    if (t < nb) boffs[t] = sh[t] - v;
    if (t == 127) ptr[n] = sh[127];
}

__global__ __launch_bounds__(1024) void scan3_kernel(int* __restrict__ ptr,
        const int* __restrict__ boffs, int n) {
    int i = blockIdx.x * 1024 + threadIdx.x;
    if (i < n) ptr[i] += boffs[blockIdx.x];
}

__global__ void scatter_kernel(const int* __restrict__ row, const int* __restrict__ col,
                               const float* __restrict__ val, const int* __restrict__ ptr,
                               const int* __restrict__ rank, int2* __restrict__ pairs,
                               int nnz) {
    int stride = gridDim.x * blockDim.x;
    for (int e = blockIdx.x * blockDim.x + threadIdx.x; e < nnz; e += stride)
        pairs[ptr[row[e]] + rank[e]] = make_int2(col[e], __float_as_int(val[e]));
}

// ---------------- SpMM: wave per row, lane per dim ----------------

__global__ __launch_bounds__(256) void spmm_first_kernel(const float* __restrict__ ut,
        const float* __restrict__ it,
        float* __restrict__ xout, float* __restrict__ acc,
        const int* __restrict__ ptr, const int2* __restrict__ pairs) {
    int wid = (blockIdx.x * 256 + threadIdx.x) >> 6;
    int lane = threadIdx.x & 63;
    if (wid >= NUM_NODES) return;
    int s = ptr[wid], e = ptr[wid + 1];
    float a = 0.f;
    for (int j = s; j < e; ++j) {
        int2 p = pairs[j];
        int c = p.x;
        const float* src = (c < NUM_USERS) ? (ut + (size_t)c * DIM)
                                           : (it + (size_t)(c - NUM_USERS) * DIM);
        a = fmaf(__int_as_float(p.y), src[lane], a);
    }
    size_t o = (size_t)wid * DIM + lane;
    xout[o] = a;
    acc[o] = a;
}

__global__ __launch_bounds__(256) void spmm_kernel(const float* __restrict__ xin,
        float* __restrict__ xout, float* __restrict__ acc,
        const int* __restrict__ ptr, const int2* __restrict__ pairs) {
    int wid = (blockIdx.x * 256 + threadIdx.x) >> 6;
    int lane = threadIdx.x & 63;
    if (wid >= NUM_NODES) return;
    int s = ptr[wid], e = ptr[wid + 1];
    float a = 0.f;
    int j = s;
    for (; j + 4 <= e; j += 4) {
        int2 p0 = pairs[j], p1 = pairs[j + 1], p2 = pairs[j + 2], p3 = pairs[j + 3];
        float x0 = xin[(size_t)p0.x * DIM + lane];
        float x1 = xin[(size_t)p1.x * DIM + lane];
        float x2 = xin[(size_t)p2.x * DIM + lane];
        float x3 = xin[(size_t)p3.x * DIM + lane];
        a = fmaf(__int_as_float(p0.y), x0, a);
        a = fmaf(__int_as_float(p1.y), x1, a);
        a = fmaf(__int_as_float(p2.y), x2, a);
        a = fmaf(__int_as_float(p3.y), x3, a);
    }
    for (; j < e; ++j) {
        int2 p = pairs[j];
        a = fmaf(__int_as_float(p.y), xin[(size_t)p.x * DIM + lane], a);
    }
    size_t o = (size_t)wid * DIM + lane;
    xout[o] = a;
    acc[o] += a;
}

// ---------------- BPR + reg ----------------

__device__ __forceinline__ float wave_sum(float v) {
    for (int o = 32; o; o >>= 1) v += __shfl_xor(v, o);
    return v;
}

__global__ __launch_bounds__(256) void loss1_kernel(const float* __restrict__ acc,
        const float* __restrict__ ut, const float* __restrict__ it,
        const int* __restrict__ user, const int* __restrict__ pos,
        const int* __restrict__ neg, float* __restrict__ oacc) {
    int lane = threadIdx.x & 63;
    int wib = threadIdx.x >> 6;
    int gw = blockIdx.x * 4 + wib;
    int nw = gridDim.x * 4;
    float sp_sum = 0.f, rg_sum = 0.f;
    for (int b = gw; b < BATCH; b += nw) {
        int iu = user[b], ip = pos[b], in_ = neg[b];
        float u = acc[(size_t)iu * DIM + lane] * (1.f / 3.f);
        float p = acc[((size_t)NUM_USERS + ip) * DIM + lane] * (1.f / 3.f);
        float n = acc[((size_t)NUM_USERS + in_) * DIM + lane] * (1.f / 3.f);
        float dp = wave_sum(u * p);
        float dn = wave_sum(u * n);
        float x = dn - dp;
        float sp = fmaxf(x, 0.f) + log1pf(expf(-fabsf(x)));
        float eu = ut[(size_t)iu * DIM + lane];
        float ep = it[(size_t)ip * DIM + lane];
        float en = it[(size_t)in_ * DIM + lane];
        float r = wave_sum(eu * eu + ep * ep + en * en);
        if (lane == 0) { sp_sum += sp; rg_sum += r; }
    }
    __shared__ float lsp[4], lrg[4];
    if (lane == 0) { lsp[wib] = sp_sum; lrg[wib] = rg_sum; }
    __syncthreads();
    if (threadIdx.x == 0) {
        atomicAdd(&oacc[0], lsp[0] + lsp[1] + lsp[2] + lsp[3]);
        atomicAdd(&oacc[1], lrg[0] + lrg[1] + lrg[2] + lrg[3]);
    }
}

// ---------------- normalize gathered rows -> bf16 ----------------

__global__ __launch_bounds__(256) void norm_kernel(const float* __restrict__ acc,
        const int* __restrict__ user, const int* __restrict__ pos,
        __hip_bfloat16* __restrict__ vnh, float* __restrict__ posv) {
    int lane = threadIdx.x & 63;
    int gw = (blockIdx.x * 256 + threadIdx.x) >> 6;   // 0..8191
    if (gw >= 2 * BATCH) return;
    int node = (gw < BATCH) ? user[gw] : (NUM_USERS + pos[gw - BATCH]);
    float v = acc[(size_t)node * DIM + lane] * (1.f / 3.f);
    float n2 = wave_sum(v * v);
    float nrm = sqrtf(n2);
    float inv = 1.f / (nrm + 1e-8f);
    vnh[(size_t)gw * DIM + lane] = __float2bfloat16(v * inv);
    if (lane == 0) posv[gw] = n2 * inv * inv * TEMP_INV;
}

// ---------------- MFMA gram + fixed-shift sumexp ----------------
// Grid 2048 blocks x 4 waves. block b: side = b>>10, itile = (b>>2)&255,
// jgroup = b&3. Wave handles i-tile (16 rows) x 16 j-tiles.
// S = V.V^T is symmetric, so any A/B fragment-role transpose is harmless.

__global__ __launch_bounds__(256) void gram2_kernel(const __hip_bfloat16* __restrict__ vnh_,
                                                    float* __restrict__ rowsum) {
    const __bf16* vnh = (const __bf16*)vnh_;
    int b = blockIdx.x;
    int side = b >> 10;
    int itile = (b >> 2) & 255;
    int jgroup = b & 3;
    int wave = threadIdx.x >> 6;
    int lane = threadIdx.x & 63;
    int jsub = jgroup * 4 + wave;            // 0..15
    const __bf16* base = vnh + (size_t)side * BATCH * DIM;
    int i0 = itile * 16;
    int row = lane & 15;
    int koff = (lane >> 4) * 8;
    bf16x8 a0 = *(const bf16x8*)&base[(i0 + row) * DIM + koff];
    bf16x8 a1 = *(const bf16x8*)&base[(i0 + row) * DIM + 32 + koff];
    float rs[4] = {0.f, 0.f, 0.f, 0.f};
    for (int t = 0; t < 16; ++t) {
        int j0 = (jsub + t * 16) * 16;
        bf16x8 b0 = *(const bf16x8*)&base[(j0 + row) * DIM + koff];
        bf16x8 b1 = *(const bf16x8*)&base[(j0 + row) * DIM + 32 + koff];
        f32x4 c = {0.f, 0.f, 0.f, 0.f};
        c = __builtin_amdgcn_mfma_f32_16x16x32_bf16(a0, b0, c, 0, 0, 0);
        c = __builtin_amdgcn_mfma_f32_16x16x32_bf16(a1, b1, c, 0, 0, 0);
        #pragma unroll
        for (int r = 0; r < 4; ++r)
            rs[r] += __expf(TEMP_INV * c[r] - TEMP_INV);   // logit-5 <= 0
    }
    #pragma unroll
    for (int r = 0; r < 4; ++r) {
        rs[r] += __shfl_xor(rs[r], 1);
        rs[r] += __shfl_xor(rs[r], 2);
        rs[r] += __shfl_xor(rs[r], 4);
        rs[r] += __shfl_xor(rs[r], 8);
    }
    if ((lane & 15) == 0) {
        #pragma unroll
        for (int r = 0; r < 4; ++r)
            atomicAdd(&rowsum[side * BATCH + i0 + (lane >> 4) * 4 + r], rs[r]);
    }
}

__global__ __launch_bounds__(256) void lse_kernel(const float* __restrict__ rowsum,
        const float* __restrict__ posv, float* __restrict__ oacc) {
    int idx = blockIdx.x * 256 + threadIdx.x;
    float c = 0.f;
    if (idx < 2 * BATCH) {
        float s = rowsum[idx];
        c = TEMP_INV + logf(s) - posv[idx];
    }
    c = wave_sum(c);
    __shared__ float l[4];
    int lane = threadIdx.x & 63, w = threadIdx.x >> 6;
    if (lane == 0) l[w] = c;
    __syncthreads();
    if (threadIdx.x == 0) atomicAdd(&oacc[2], l[0] + l[1] + l[2] + l[3]);
}

__global__ void final_kernel(const float* __restrict__ oacc, float* __restrict__ out) {
    out[0] = oacc[0] * (1.f / BATCH);
    out[1] = oacc[1] * (1e-4f * 0.5f / BATCH);
    out[2] = oacc[2] * (0.1f / BATCH);
}

// ---------------- launch ----------------

extern "C" void kernel_launch(void* const* d_in, const int* in_sizes, int n_in,
                              void* d_out, int out_size, void* d_ws, size_t ws_size,
                              hipStream_t stream) {
    const float* user_table = (const float*)d_in[0];
    const float* item_table = (const float*)d_in[1];
    const float* edge_val   = (const float*)d_in[2];
    const int*   user       = (const int*)d_in[3];
    const int*   positive   = (const int*)d_in[4];
    const int*   negative   = (const int*)d_in[5];
    const int*   edge_row   = (const int*)d_in[6];
    const int*   edge_col   = (const int*)d_in[7];
    float* out = (float*)d_out;

    char* w = (char*)d_ws;
    auto alloc = [&](size_t bytes) {
        char* p = w;
        w += (bytes + 255) & ~(size_t)255;
        return p;
    };
    int*   row_ptr = (int*)alloc((NUM_NODES + 1) * sizeof(int));
    int*   cnt     = (int*)alloc(NUM_NODES * sizeof(int));
    int*   rank    = (int*)alloc((size_t)NNZ * sizeof(int));
    int*   bsum    = (int*)alloc(SCAN_BLOCKS * sizeof(int));
    int*   boffs   = (int*)alloc(SCAN_BLOCKS * sizeof(int));
    int2*  pairs   = (int2*)alloc((size_t)NNZ * sizeof(int2));
    float* xA      = (float*)alloc((size_t)NUM_NODES * DIM * sizeof(float));
    float* xB      = (float*)alloc((size_t)NUM_NODES * DIM * sizeof(float));
    float* acc     = (float*)alloc((size_t)NUM_NODES * DIM * sizeof(float));
    __hip_bfloat16* vnh = (__hip_bfloat16*)alloc((size_t)2 * BATCH * DIM * sizeof(__hip_bfloat16));
    float* posv    = (float*)alloc(2 * BATCH * sizeof(float));
    float* rowsum  = (float*)alloc(2 * BATCH * sizeof(float));
    float* oacc    = (float*)alloc(4 * sizeof(float));

    hipMemsetAsync(cnt, 0, NUM_NODES * sizeof(int), stream);
    hipMemsetAsync(oacc, 0, 4 * sizeof(float), stream);
    hipMemsetAsync(rowsum, 0, 2 * BATCH * sizeof(float), stream);

    hist_kernel<<<2048, 256, 0, stream>>>(edge_row, cnt, rank, NNZ);
    scan1_kernel<<<SCAN_BLOCKS, 1024, 0, stream>>>(cnt, row_ptr, bsum, NUM_NODES);
    scan2_kernel<<<1, 128, 0, stream>>>(bsum, boffs, row_ptr, SCAN_BLOCKS, NUM_NODES);
    scan3_kernel<<<SCAN_BLOCKS, 1024, 0, stream>>>(row_ptr, boffs, NUM_NODES);
    scatter_kernel<<<2048, 256, 0, stream>>>(edge_row, edge_col, edge_val,
                                             row_ptr, rank, pairs, NNZ);

    const int SPMM_BLOCKS = (NUM_NODES + 3) / 4;   // 4 waves (rows) per 256-thr block
    spmm_first_kernel<<<SPMM_BLOCKS, 256, 0, stream>>>(user_table, item_table,
                                                       xB, acc, row_ptr, pairs);
    spmm_kernel<<<SPMM_BLOCKS, 256, 0, stream>>>(xB, xA, acc, row_ptr, pairs);
    spmm_kernel<<<SPMM_BLOCKS, 256, 0, stream>>>(xA, xB, acc, row_ptr, pairs);

    loss1_kernel<<<256, 256, 0, stream>>>(acc, user_table, item_table,
                                          user, positive, negative, oacc);
    norm_kernel<<<(2 * BATCH) / 4, 256, 0, stream>>>(acc, user, positive, vnh, posv);
    gram2_kernel<<<2048, 256, 0, stream>>>(vnh, rowsum);
    lse_kernel<<<(2 * BATCH + 255) / 256, 256, 0, stream>>>(rowsum, posv, oacc);
    final_kernel<<<1, 1, 0, stream>>>(oacc, out);
}

// Round 4
// 354.229 us; speedup vs baseline: 1.5267x; 1.5267x over previous
//
#include <hip/hip_runtime.h>
#include <hip/hip_bf16.h>
#include <math.h>

#define NUM_USERS 60000
#define NUM_ITEMS 40000
#define NUM_NODES (NUM_USERS + NUM_ITEMS)
#define NNZ 2000000
#define DIM 64
#define BATCH 4096
#define TEMP_INV 5.0f   // 1/0.2
#define SCAN_BLOCKS ((NUM_NODES + 1023) / 1024)   // 98
#define PAIR_CAP (NNZ + NUM_NODES * 8)

typedef __attribute__((ext_vector_type(8))) __bf16 bf16x8;
typedef __attribute__((ext_vector_type(4))) float f32x4;

__device__ __forceinline__ ushort f2bf(float f) {           // RNE, finite inputs
    uint u = __float_as_uint(f);
    return (ushort)((u + 0x7FFF + ((u >> 16) & 1)) >> 16);
}
__device__ __forceinline__ float bf2f(ushort u) {
    return __uint_as_float((uint)u << 16);
}

// ---------------- table concat + f32->bf16 convert ----------------

__global__ __launch_bounds__(256) void cvt_kernel(const float* __restrict__ ut,
        const float* __restrict__ it, ushort* __restrict__ x0) {
    int g = blockIdx.x * 256 + threadIdx.x;
    const int total4 = NUM_NODES * DIM / 4;
    if (g >= total4) return;
    size_t off = (size_t)g * 4;
    const float* src = (off < (size_t)NUM_USERS * DIM)
                           ? ut + off
                           : it + (off - (size_t)NUM_USERS * DIM);
    float4 v = *(const float4*)src;
    ushort4 o;
    o.x = f2bf(v.x); o.y = f2bf(v.y); o.z = f2bf(v.z); o.w = f2bf(v.w);
    *(ushort4*)&x0[off] = o;
}

// ---------------- CSR build (rows padded to multiple of 8) ----------------

__global__ void hist_kernel(const int* __restrict__ row, int* __restrict__ cnt,
                            int* __restrict__ rank, int nnz) {
    int stride = gridDim.x * blockDim.x;
    for (int e = blockIdx.x * blockDim.x + threadIdx.x; e < nnz; e += stride)
        rank[e] = atomicAdd(&cnt[row[e]], 1);
}

__global__ __launch_bounds__(1024) void scan1_kernel(const int* __restrict__ cnt,
        int* __restrict__ ptr, int* __restrict__ bsum, int n) {
    __shared__ int sh[1024];
    int t = threadIdx.x;
    int i = blockIdx.x * 1024 + t;
    int v = (i < n) ? ((cnt[i] + 7) & ~7) : 0;   // padded row length
    sh[t] = v;
    __syncthreads();
    for (int d = 1; d < 1024; d <<= 1) {
        int w = (t >= d) ? sh[t - d] : 0;
        __syncthreads();
        sh[t] += w;
        __syncthreads();
    }
    int incl = sh[t];
    if (i < n) ptr[i] = incl - v;
    if (t == 1023) bsum[blockIdx.x] = incl;
}

__global__ __launch_bounds__(128) void scan2_kernel(const int* __restrict__ bsum,
        int* __restrict__ boffs, int* __restrict__ ptr, int nb, int n) {
    __shared__ int sh[128];
    int t = threadIdx.x;
    int v = (t < nb) ? bsum[t] : 0;
    sh[t] = v;
    __syncthreads();
    for (int d = 1; d < 128; d <<= 1) {
        int w = (t >= d) ? sh[t - d] : 0;
        __syncthreads();
        sh[t] += w;
        __syncthreads();
    }
    if (t < nb) boffs[t] = sh[t] - v;
    if (t == 127) ptr[n] = sh[127];
}

__global__ __launch_bounds__(1024) void scan3_kernel(int* __restrict__ ptr,
        const int* __restrict__ boffs, int n) {
    int i = blockIdx.x * 1024 + threadIdx.x;
    if (i < n) ptr[i] += boffs[blockIdx.x];
}

__global__ void scatter_kernel(const int* __restrict__ row, const int* __restrict__ col,
                               const float* __restrict__ val, const int* __restrict__ ptr,
                               const int* __restrict__ rank, int2* __restrict__ pairs,
                               int nnz) {
    int stride = gridDim.x * blockDim.x;
    for (int e = blockIdx.x * blockDim.x + threadIdx.x; e < nnz; e += stride)
        pairs[ptr[row[e]] + rank[e]] = make_int2(col[e], __float_as_int(val[e]));
}

// ---------------- SpMM: wave per row, lane per dim, bf16 in/out ----------------
// Row length is a multiple of 8; pad slots are (col=0, val=0) from the memset.

__global__ __launch_bounds__(256) void spmm_kernel(const ushort* __restrict__ xin,
        ushort* __restrict__ xout,
        const int* __restrict__ ptr, const int2* __restrict__ pairs) {
    int wid = (blockIdx.x * 256 + threadIdx.x) >> 6;
    int lane = threadIdx.x & 63;
    if (wid >= NUM_NODES) return;
    int s = ptr[wid], e = ptr[wid + 1];
    float a0 = 0.f, a1 = 0.f;
    for (int j = s; j < e; j += 8) {
        int2 p = pairs[j + (lane & 7)];   // one coalesced load covers 8 edges
        #pragma unroll
        for (int k = 0; k < 8; ++k) {
            int c = __shfl(p.x, k);
            float v = __int_as_float(__shfl(p.y, k));
            float xv = bf2f(xin[c * DIM + lane]);
            if (k & 1) a1 = fmaf(v, xv, a1); else a0 = fmaf(v, xv, a0);
        }
    }
    xout[wid * DIM + lane] = f2bf(a0 + a1);
}

// ---------------- BPR + reg ----------------

__device__ __forceinline__ float wave_sum(float v) {
    for (int o = 32; o; o >>= 1) v += __shfl_xor(v, o);
    return v;
}

__device__ __forceinline__ float acc3(const ushort* x1, const ushort* x2,
                                      const ushort* x3, int node, int lane) {
    int o = node * DIM + lane;
    return (bf2f(x1[o]) + bf2f(x2[o]) + bf2f(x3[o])) * (1.f / 3.f);
}

__global__ __launch_bounds__(256) void loss1_kernel(const ushort* __restrict__ x1,
        const ushort* __restrict__ x2, const ushort* __restrict__ x3,
        const float* __restrict__ ut, const float* __restrict__ it,
        const int* __restrict__ user, const int* __restrict__ pos,
        const int* __restrict__ neg, float* __restrict__ oacc) {
    int lane = threadIdx.x & 63;
    int wib = threadIdx.x >> 6;
    int gw = blockIdx.x * 4 + wib;
    int nw = gridDim.x * 4;
    float sp_sum = 0.f, rg_sum = 0.f;
    for (int b = gw; b < BATCH; b += nw) {
        int iu = user[b], ip = pos[b], in_ = neg[b];
        float u = acc3(x1, x2, x3, iu, lane);
        float p = acc3(x1, x2, x3, NUM_USERS + ip, lane);
        float n = acc3(x1, x2, x3, NUM_USERS + in_, lane);
        float dp = wave_sum(u * p);
        float dn = wave_sum(u * n);
        float x = dn - dp;
        float sp = fmaxf(x, 0.f) + log1pf(expf(-fabsf(x)));
        float eu = ut[(size_t)iu * DIM + lane];
        float ep = it[(size_t)ip * DIM + lane];
        float en = it[(size_t)in_ * DIM + lane];
        float r = wave_sum(eu * eu + ep * ep + en * en);
        if (lane == 0) { sp_sum += sp; rg_sum += r; }
    }
    __shared__ float lsp[4], lrg[4];
    if (lane == 0) { lsp[wib] = sp_sum; lrg[wib] = rg_sum; }
    __syncthreads();
    if (threadIdx.x == 0) {
        atomicAdd(&oacc[0], lsp[0] + lsp[1] + lsp[2] + lsp[3]);
        atomicAdd(&oacc[1], lrg[0] + lrg[1] + lrg[2] + lrg[3]);
    }
}

// ---------------- normalize gathered rows -> bf16 ----------------

__global__ __launch_bounds__(256) void norm_kernel(const ushort* __restrict__ x1,
        const ushort* __restrict__ x2, const ushort* __restrict__ x3,
        const int* __restrict__ user, const int* __restrict__ pos,
        ushort* __restrict__ vnh, float* __restrict__ posv) {
    int lane = threadIdx.x & 63;
    int gw = (blockIdx.x * 256 + threadIdx.x) >> 6;   // 0..8191
    if (gw >= 2 * BATCH) return;
    int node = (gw < BATCH) ? user[gw] : (NUM_USERS + pos[gw - BATCH]);
    float v = acc3(x1, x2, x3, node, lane);
    float n2 = wave_sum(v * v);
    float nrm = sqrtf(n2);
    float inv = 1.f / (nrm + 1e-8f);
    vnh[gw * DIM + lane] = f2bf(v * inv);
    if (lane == 0) posv[gw] = n2 * inv * inv * TEMP_INV;
}

// ---------------- MFMA gram + fixed-shift sumexp ----------------

__global__ __launch_bounds__(256) void gram2_kernel(const ushort* __restrict__ vnh_,
                                                    float* __restrict__ rowsum) {
    const __bf16* vnh = (const __bf16*)vnh_;
    int b = blockIdx.x;
    int side = b >> 10;
    int itile = (b >> 2) & 255;
    int jgroup = b & 3;
    int wave = threadIdx.x >> 6;
    int lane = threadIdx.x & 63;
    int jsub = jgroup * 4 + wave;            // 0..15
    const __bf16* base = vnh + (size_t)side * BATCH * DIM;
    int i0 = itile * 16;
    int row = lane & 15;
    int koff = (lane >> 4) * 8;
    bf16x8 a0 = *(const bf16x8*)&base[(i0 + row) * DIM + koff];
    bf16x8 a1 = *(const bf16x8*)&base[(i0 + row) * DIM + 32 + koff];
    float rs[4] = {0.f, 0.f, 0.f, 0.f};
    for (int t = 0; t < 16; ++t) {
        int j0 = (jsub + t * 16) * 16;
        bf16x8 b0 = *(const bf16x8*)&base[(j0 + row) * DIM + koff];
        bf16x8 b1 = *(const bf16x8*)&base[(j0 + row) * DIM + 32 + koff];
        f32x4 c = {0.f, 0.f, 0.f, 0.f};
        c = __builtin_amdgcn_mfma_f32_16x16x32_bf16(a0, b0, c, 0, 0, 0);
        c = __builtin_amdgcn_mfma_f32_16x16x32_bf16(a1, b1, c, 0, 0, 0);
        #pragma unroll
        for (int r = 0; r < 4; ++r)
            rs[r] += __expf(TEMP_INV * c[r] - TEMP_INV);   // logit-5 <= 0
    }
    #pragma unroll
    for (int r = 0; r < 4; ++r) {
        rs[r] += __shfl_xor(rs[r], 1);
        rs[r] += __shfl_xor(rs[r], 2);
        rs[r] += __shfl_xor(rs[r], 4);
        rs[r] += __shfl_xor(rs[r], 8);
    }
    if ((lane & 15) == 0) {
        #pragma unroll
        for (int r = 0; r < 4; ++r)
            atomicAdd(&rowsum[side * BATCH + i0 + (lane >> 4) * 4 + r], rs[r]);
    }
}

__global__ __launch_bounds__(256) void lse_kernel(const float* __restrict__ rowsum,
        const float* __restrict__ posv, float* __restrict__ oacc) {
    int idx = blockIdx.x * 256 + threadIdx.x;
    float c = 0.f;
    if (idx < 2 * BATCH) {
        float s = rowsum[idx];
        c = TEMP_INV + logf(s) - posv[idx];
    }
    c = wave_sum(c);
    __shared__ float l[4];
    int lane = threadIdx.x & 63, w = threadIdx.x >> 6;
    if (lane == 0) l[w] = c;
    __syncthreads();
    if (threadIdx.x == 0) atomicAdd(&oacc[2], l[0] + l[1] + l[2] + l[3]);
}

__global__ void final_kernel(const float* __restrict__ oacc, float* __restrict__ out) {
    out[0] = oacc[0] * (1.f / BATCH);
    out[1] = oacc[1] * (1e-4f * 0.5f / BATCH);
    out[2] = oacc[2] * (0.1f / BATCH);
}

// ---------------- launch ----------------

extern "C" void kernel_launch(void* const* d_in, const int* in_sizes, int n_in,
                              void* d_out, int out_size, void* d_ws, size_t ws_size,
                              hipStream_t stream) {
    const float* user_table = (const float*)d_in[0];
    const float* item_table = (const float*)d_in[1];
    const float* edge_val   = (const float*)d_in[2];
    const int*   user       = (const int*)d_in[3];
    const int*   positive   = (const int*)d_in[4];
    const int*   negative   = (const int*)d_in[5];
    const int*   edge_row   = (const int*)d_in[6];
    const int*   edge_col   = (const int*)d_in[7];
    float* out = (float*)d_out;

    char* w = (char*)d_ws;
    auto alloc = [&](size_t bytes) {
        char* p = w;
        w += (bytes + 255) & ~(size_t)255;
        return p;
    };
    int*    row_ptr = (int*)alloc((NUM_NODES + 1) * sizeof(int));
    int*    cnt     = (int*)alloc(NUM_NODES * sizeof(int));
    int*    rank    = (int*)alloc((size_t)NNZ * sizeof(int));
    int*    bsum    = (int*)alloc(SCAN_BLOCKS * sizeof(int));
    int*    boffs   = (int*)alloc(SCAN_BLOCKS * sizeof(int));
    int2*   pairs   = (int2*)alloc((size_t)PAIR_CAP * sizeof(int2));
    ushort* x0h     = (ushort*)alloc((size_t)NUM_NODES * DIM * sizeof(ushort));
    ushort* x1h     = (ushort*)alloc((size_t)NUM_NODES * DIM * sizeof(ushort));
    ushort* x2h     = (ushort*)alloc((size_t)NUM_NODES * DIM * sizeof(ushort));
    ushort* x3h     = (ushort*)alloc((size_t)NUM_NODES * DIM * sizeof(ushort));
    ushort* vnh     = (ushort*)alloc((size_t)2 * BATCH * DIM * sizeof(ushort));
    float*  posv    = (float*)alloc(2 * BATCH * sizeof(float));
    float*  rowsum  = (float*)alloc(2 * BATCH * sizeof(float));
    float*  oacc    = (float*)alloc(4 * sizeof(float));

    hipMemsetAsync(cnt, 0, NUM_NODES * sizeof(int), stream);
    hipMemsetAsync(oacc, 0, 4 * sizeof(float), stream);
    hipMemsetAsync(rowsum, 0, 2 * BATCH * sizeof(float), stream);
    hipMemsetAsync(pairs, 0, (size_t)PAIR_CAP * sizeof(int2), stream);

    cvt_kernel<<<(NUM_NODES * DIM / 4 + 255) / 256, 256, 0, stream>>>(
        user_table, item_table, x0h);
    hist_kernel<<<2048, 256, 0, stream>>>(edge_row, cnt, rank, NNZ);
    scan1_kernel<<<SCAN_BLOCKS, 1024, 0, stream>>>(cnt, row_ptr, bsum, NUM_NODES);
    scan2_kernel<<<1, 128, 0, stream>>>(bsum, boffs, row_ptr, SCAN_BLOCKS, NUM_NODES);
    scan3_kernel<<<SCAN_BLOCKS, 1024, 0, stream>>>(row_ptr, boffs, NUM_NODES);
    scatter_kernel<<<2048, 256, 0, stream>>>(edge_row, edge_col, edge_val,
                                             row_ptr, rank, pairs, NNZ);

    const int SPMM_BLOCKS = (NUM_NODES + 3) / 4;   // 4 waves (rows) per 256-thr block
    spmm_kernel<<<SPMM_BLOCKS, 256, 0, stream>>>(x0h, x1h, row_ptr, pairs);
    spmm_kernel<<<SPMM_BLOCKS, 256, 0, stream>>>(x1h, x2h, row_ptr, pairs);
    spmm_kernel<<<SPMM_BLOCKS, 256, 0, stream>>>(x2h, x3h, row_ptr, pairs);

    loss1_kernel<<<256, 256, 0, stream>>>(x1h, x2h, x3h, user_table, item_table,
                                          user, positive, negative, oacc);
    norm_kernel<<<(2 * BATCH) / 4, 256, 0, stream>>>(x1h, x2h, x3h, user, positive,
                                                     vnh, posv);
    gram2_kernel<<<2048, 256, 0, stream>>>(vnh, rowsum);
    lse_kernel<<<(2 * BATCH + 255) / 256, 256, 0, stream>>>(rowsum, posv, oacc);
    final_kernel<<<1, 1, 0, stream>>>(oacc, out);
}